// Round 1
// baseline (224.973 us; speedup 1.0000x reference)
//
#include <hip/hip_runtime.h>
#include <math.h>

#define HID 64

// ---------------------------------------------------------------------------
// Edge stage: msg = MLP3([nf[src], nf[dst], ef]) ; agg[dst] += msg
// One thread per edge. Weight indices are compile-time constants + uniform
// base pointers -> compiler should emit scalar (s_load) weight fetches.
// h1[k] recomputed inside k-loop to keep VGPR pressure ~ acc[64].
// ---------------------------------------------------------------------------
__global__ __launch_bounds__(256) void edge_msg_kernel(
    const float* __restrict__ nf, const float* __restrict__ ef,
    const int* __restrict__ src, const int* __restrict__ dst,
    const float* __restrict__ w1, const float* __restrict__ b1,
    const float* __restrict__ w2, const float* __restrict__ b2,
    const float* __restrict__ w3, const float* __restrict__ b3,
    float* __restrict__ agg, int E)
{
    int e = blockIdx.x * blockDim.x + threadIdx.x;
    if (e >= E) return;

    float a = nf[src[e]];
    float b = nf[dst[e]];
    float c = ef[e];

    float acc[HID];
#pragma unroll
    for (int j = 0; j < HID; ++j) acc[j] = b2[j];

#pragma unroll
    for (int k = 0; k < HID; ++k) {
        float h = fmaf(a, w1[k],
                  fmaf(b, w1[HID + k],
                  fmaf(c, w1[2 * HID + k], b1[k])));
        h = fmaxf(h, 0.0f);
#pragma unroll
        for (int j = 0; j < HID; ++j)
            acc[j] = fmaf(h, w2[k * HID + j], acc[j]);
    }

    float msg = b3[0];
#pragma unroll
    for (int j = 0; j < HID; ++j)
        msg = fmaf(fmaxf(acc[j], 0.0f), w3[j], msg);

    atomicAdd(&agg[dst[e]], msg);
}

// ---------------------------------------------------------------------------
// Node stage: unf = MLP3([nf, agg]) ; node_out = sigmoid(MLP3(unf)) ;
// rd[graph_id] += node_out.   One thread per node, both MLPs fused.
// ---------------------------------------------------------------------------
__global__ __launch_bounds__(256) void node_kernel(
    const float* __restrict__ nf, const float* __restrict__ agg,
    const int* __restrict__ gid,
    const float* __restrict__ nw1, const float* __restrict__ nb1,
    const float* __restrict__ nw2, const float* __restrict__ nb2,
    const float* __restrict__ nw3, const float* __restrict__ nb3,
    const float* __restrict__ mw1, const float* __restrict__ mb1,
    const float* __restrict__ mw2, const float* __restrict__ mb2,
    const float* __restrict__ mw3, const float* __restrict__ mb3,
    float* __restrict__ rd, int N)
{
    int i = blockIdx.x * blockDim.x + threadIdx.x;
    if (i >= N) return;

    float x0 = nf[i];
    float x1 = agg[i];

    // ---- node model: [x0, x1] -> unf (scalar) ----
    float acc[HID];
#pragma unroll
    for (int j = 0; j < HID; ++j) acc[j] = nb2[j];
#pragma unroll
    for (int k = 0; k < HID; ++k) {
        float h = fmaf(x0, nw1[k], fmaf(x1, nw1[HID + k], nb1[k]));
        h = fmaxf(h, 0.0f);
#pragma unroll
        for (int j = 0; j < HID; ++j)
            acc[j] = fmaf(h, nw2[k * HID + j], acc[j]);
    }
    float unf = nb3[0];
#pragma unroll
    for (int j = 0; j < HID; ++j)
        unf = fmaf(fmaxf(acc[j], 0.0f), nw3[j], unf);

    // ---- node-wise model: unf -> sigmoid(out) ----
#pragma unroll
    for (int j = 0; j < HID; ++j) acc[j] = mb2[j];
#pragma unroll
    for (int k = 0; k < HID; ++k) {
        float h = fmaf(unf, mw1[k], mb1[k]);
        h = fmaxf(h, 0.0f);
#pragma unroll
        for (int j = 0; j < HID; ++j)
            acc[j] = fmaf(h, mw2[k * HID + j], acc[j]);
    }
    float o = mb3[0];
#pragma unroll
    for (int j = 0; j < HID; ++j)
        o = fmaf(fmaxf(acc[j], 0.0f), mw3[j], o);

    float node_out = 1.0f / (1.0f + expf(-o));
    atomicAdd(&rd[gid[i]], node_out);
}

// ---------------------------------------------------------------------------
// Readout: out[g] = sigmoid(rd[g])
// ---------------------------------------------------------------------------
__global__ void readout_kernel(const float* __restrict__ rd,
                               float* __restrict__ out, int G)
{
    int g = blockIdx.x * blockDim.x + threadIdx.x;
    if (g < G) out[g] = 1.0f / (1.0f + expf(-rd[g]));
}

extern "C" void kernel_launch(void* const* d_in, const int* in_sizes, int n_in,
                              void* d_out, int out_size, void* d_ws, size_t ws_size,
                              hipStream_t stream)
{
    const float* nf  = (const float*)d_in[0];
    const float* ef  = (const float*)d_in[1];
    const int*   src = (const int*)  d_in[2];
    const int*   dst = (const int*)  d_in[3];
    const int*   gid = (const int*)  d_in[4];

    const float* e_w1 = (const float*)d_in[5];
    const float* e_b1 = (const float*)d_in[6];
    const float* e_w2 = (const float*)d_in[7];
    const float* e_b2 = (const float*)d_in[8];
    const float* e_w3 = (const float*)d_in[9];
    const float* e_b3 = (const float*)d_in[10];

    const float* n_w1 = (const float*)d_in[11];
    const float* n_b1 = (const float*)d_in[12];
    const float* n_w2 = (const float*)d_in[13];
    const float* n_b2 = (const float*)d_in[14];
    const float* n_w3 = (const float*)d_in[15];
    const float* n_b3 = (const float*)d_in[16];

    const float* m_w1 = (const float*)d_in[17];
    const float* m_b1 = (const float*)d_in[18];
    const float* m_w2 = (const float*)d_in[19];
    const float* m_b2 = (const float*)d_in[20];
    const float* m_w3 = (const float*)d_in[21];
    const float* m_b3 = (const float*)d_in[22];

    const int N = in_sizes[0];   // 50000 nodes
    const int E = in_sizes[2];   // 1600000 edges
    const int G = out_size;      // 512 graphs

    float* agg = (float*)d_ws;        // N floats
    float* rd  = agg + N;             // G floats
    float* out = (float*)d_out;

    hipMemsetAsync(d_ws, 0, (size_t)(N + G) * sizeof(float), stream);

    edge_msg_kernel<<<(E + 255) / 256, 256, 0, stream>>>(
        nf, ef, src, dst, e_w1, e_b1, e_w2, e_b2, e_w3, e_b3, agg, E);

    node_kernel<<<(N + 255) / 256, 256, 0, stream>>>(
        nf, agg, gid,
        n_w1, n_b1, n_w2, n_b2, n_w3, n_b3,
        m_w1, m_b1, m_w2, m_b2, m_w3, m_b3,
        rd, N);

    readout_kernel<<<(G + 255) / 256, 256, 0, stream>>>(rd, out, G);
}

// Round 2
// 181.445 us; speedup vs baseline: 1.2399x; 1.2399x over previous
//
#include <hip/hip_runtime.h>
#include <math.h>

#define HID 64

typedef __attribute__((ext_vector_type(8))) short short8;
typedef __attribute__((ext_vector_type(4))) float f32x4;

union FragU {
    uint4 q;
    short8 v;
    uint32_t u[4];
};

__device__ __forceinline__ uint32_t cvt_pk_bf16(float lo, float hi) {
    uint32_t r;
    asm("v_cvt_pk_bf16_f32 %0, %1, %2" : "=v"(r) : "v"(lo), "v"(hi));
    return r;
}

// ---------------------------------------------------------------------------
// Edge stage (MFMA): msg = MLP3([nf[src], nf[dst], ef]) ; agg[dst] += msg
// Per wave: 64 edges/batch. Layer1 (K=3) on VALU, 1 edge/lane -> bf16 ->
// LDS (xor-swizzled 16B chunks). Layer2 (64x64) via mfma_f32_16x16x32_bf16,
// A = W2^T (4 j-tiles x 2 k-halves, preloaded), B = h1 tile from LDS.
// Layer3 folded into epilogue: relu(acc)*w3, shfl-reduce over j, atomicAdd.
// ---------------------------------------------------------------------------
__global__ __launch_bounds__(256) void edge_mfma_kernel(
    const float* __restrict__ nf, const float* __restrict__ ef,
    const int* __restrict__ src, const int* __restrict__ dst,
    const float* __restrict__ w1, const float* __restrict__ b1,
    const float* __restrict__ w2, const float* __restrict__ b2,
    const float* __restrict__ w3, const float* __restrict__ b3,
    float* __restrict__ agg, int E)
{
    __shared__ uint4 hbuf[256 * 8];   // 256 rows x 128B (64 bf16), 16B chunks xor-swizzled by row&7

    const int tid  = threadIdx.x;
    const int lane = tid & 63;
    const int wid  = tid >> 6;
    const int g    = lane >> 4;      // k-slice group (0..3)
    const int eL   = lane & 15;      // column within tile

    // ---- one-time: A-fragments = W2^T  (A[i][k] = w2[k][16t+i], i=eL) ----
    FragU af[4][2];
#pragma unroll
    for (int t = 0; t < 4; ++t)
#pragma unroll
        for (int h = 0; h < 2; ++h)
#pragma unroll
            for (int e2 = 0; e2 < 4; ++e2) {
                int k0 = h * 32 + g * 8 + 2 * e2;
                float v0 = w2[(k0    ) * HID + t * 16 + eL];
                float v1 = w2[(k0 + 1) * HID + t * 16 + eL];
                af[t][h].u[e2] = cvt_pk_bf16(v0, v1);
            }

    // per-lane D-row constants: j = 16t + 4g + r
    float b2v[16], w3v[16];
#pragma unroll
    for (int t = 0; t < 4; ++t)
#pragma unroll
        for (int r = 0; r < 4; ++r) {
            int j = t * 16 + g * 4 + r;
            b2v[t * 4 + r] = b2[j];
            w3v[t * 4 + r] = w3[j];
        }
    const float b3c = b3[0];

    for (int e0 = blockIdx.x * 256; e0 < E; e0 += gridDim.x * 256) {
        int eidx = e0 + tid;
        int ei = eidx < E ? eidx : E - 1;
        float a = nf[src[ei]];
        float b = nf[dst[ei]];
        float c = ef[ei];

        // ---- layer 1: h1[k] = relu(a*w1[0][k] + b*w1[1][k] + c*w1[2][k] + b1[k]) ----
        uint32_t pk[32];
#pragma unroll
        for (int k2 = 0; k2 < 32; ++k2) {
            int k0 = 2 * k2, k1 = 2 * k2 + 1;
            float h0 = fmaxf(fmaf(a, w1[k0], fmaf(b, w1[HID + k0], fmaf(c, w1[2 * HID + k0], b1[k0]))), 0.f);
            float h1 = fmaxf(fmaf(a, w1[k1], fmaf(b, w1[HID + k1], fmaf(c, w1[2 * HID + k1], b1[k1]))), 0.f);
            pk[k2] = cvt_pk_bf16(h0, h1);
        }

        __syncthreads();   // protect previous iteration's reads
        {
            uint4* rowp = &hbuf[tid * 8];
            int sw = tid & 7;
#pragma unroll
            for (int ch = 0; ch < 8; ++ch)
                rowp[ch ^ sw] = make_uint4(pk[4 * ch], pk[4 * ch + 1], pk[4 * ch + 2], pk[4 * ch + 3]);
        }
        __syncthreads();   // publish

        // ---- layer 2 (MFMA) + layer 3 epilogue, 16 edges per set ----
#pragma unroll
        for (int s = 0; s < 4; ++s) {
            int row = wid * 64 + s * 16 + eL;
            int sw  = lane & 7;              // == row & 7
            FragU bf0, bf1;
            bf0.q = hbuf[row * 8 + ((    g) ^ sw)];   // k = g*8..g*8+7
            bf1.q = hbuf[row * 8 + ((4 + g) ^ sw)];   // k = 32+g*8..+7

            f32x4 ac[4];
#pragma unroll
            for (int t = 0; t < 4; ++t) {
                ac[t][0] = b2v[t * 4 + 0];
                ac[t][1] = b2v[t * 4 + 1];
                ac[t][2] = b2v[t * 4 + 2];
                ac[t][3] = b2v[t * 4 + 3];
                ac[t] = __builtin_amdgcn_mfma_f32_16x16x32_bf16(af[t][0].v, bf0.v, ac[t], 0, 0, 0);
                ac[t] = __builtin_amdgcn_mfma_f32_16x16x32_bf16(af[t][1].v, bf1.v, ac[t], 0, 0, 0);
            }

            float p = 0.f;
#pragma unroll
            for (int t = 0; t < 4; ++t)
#pragma unroll
                for (int r = 0; r < 4; ++r)
                    p = fmaf(fmaxf(ac[t][r], 0.f), w3v[t * 4 + r], p);

            p += __shfl_xor(p, 16);
            p += __shfl_xor(p, 32);

            if (lane < 16) {
                int ge = e0 + wid * 64 + s * 16 + lane;
                if (ge < E)
                    atomicAdd(&agg[dst[ge]], p + b3c);
            }
        }
    }
}

// ---------------------------------------------------------------------------
// Node stage: unf = MLP3([nf, agg]) ; node_out = sigmoid(MLP3(unf)) ;
// rd[graph_id] += node_out.   One thread per node, both MLPs fused.
// ---------------------------------------------------------------------------
__global__ __launch_bounds__(256) void node_kernel(
    const float* __restrict__ nf, const float* __restrict__ agg,
    const int* __restrict__ gid,
    const float* __restrict__ nw1, const float* __restrict__ nb1,
    const float* __restrict__ nw2, const float* __restrict__ nb2,
    const float* __restrict__ nw3, const float* __restrict__ nb3,
    const float* __restrict__ mw1, const float* __restrict__ mb1,
    const float* __restrict__ mw2, const float* __restrict__ mb2,
    const float* __restrict__ mw3, const float* __restrict__ mb3,
    float* __restrict__ rd, int N)
{
    int i = blockIdx.x * blockDim.x + threadIdx.x;
    if (i >= N) return;

    float x0 = nf[i];
    float x1 = agg[i];

    float acc[HID];
#pragma unroll
    for (int j = 0; j < HID; ++j) acc[j] = nb2[j];
#pragma unroll
    for (int k = 0; k < HID; ++k) {
        float h = fmaf(x0, nw1[k], fmaf(x1, nw1[HID + k], nb1[k]));
        h = fmaxf(h, 0.0f);
#pragma unroll
        for (int j = 0; j < HID; ++j)
            acc[j] = fmaf(h, nw2[k * HID + j], acc[j]);
    }
    float unf = nb3[0];
#pragma unroll
    for (int j = 0; j < HID; ++j)
        unf = fmaf(fmaxf(acc[j], 0.0f), nw3[j], unf);

#pragma unroll
    for (int j = 0; j < HID; ++j) acc[j] = mb2[j];
#pragma unroll
    for (int k = 0; k < HID; ++k) {
        float h = fmaf(unf, mw1[k], mb1[k]);
        h = fmaxf(h, 0.0f);
#pragma unroll
        for (int j = 0; j < HID; ++j)
            acc[j] = fmaf(h, mw2[k * HID + j], acc[j]);
    }
    float o = mb3[0];
#pragma unroll
    for (int j = 0; j < HID; ++j)
        o = fmaf(fmaxf(acc[j], 0.0f), mw3[j], o);

    float node_out = 1.0f / (1.0f + expf(-o));
    atomicAdd(&rd[gid[i]], node_out);
}

__global__ void readout_kernel(const float* __restrict__ rd,
                               float* __restrict__ out, int G)
{
    int g = blockIdx.x * blockDim.x + threadIdx.x;
    if (g < G) out[g] = 1.0f / (1.0f + expf(-rd[g]));
}

extern "C" void kernel_launch(void* const* d_in, const int* in_sizes, int n_in,
                              void* d_out, int out_size, void* d_ws, size_t ws_size,
                              hipStream_t stream)
{
    const float* nf  = (const float*)d_in[0];
    const float* ef  = (const float*)d_in[1];
    const int*   src = (const int*)  d_in[2];
    const int*   dst = (const int*)  d_in[3];
    const int*   gid = (const int*)  d_in[4];

    const float* e_w1 = (const float*)d_in[5];
    const float* e_b1 = (const float*)d_in[6];
    const float* e_w2 = (const float*)d_in[7];
    const float* e_b2 = (const float*)d_in[8];
    const float* e_w3 = (const float*)d_in[9];
    const float* e_b3 = (const float*)d_in[10];

    const float* n_w1 = (const float*)d_in[11];
    const float* n_b1 = (const float*)d_in[12];
    const float* n_w2 = (const float*)d_in[13];
    const float* n_b2 = (const float*)d_in[14];
    const float* n_w3 = (const float*)d_in[15];
    const float* n_b3 = (const float*)d_in[16];

    const float* m_w1 = (const float*)d_in[17];
    const float* m_b1 = (const float*)d_in[18];
    const float* m_w2 = (const float*)d_in[19];
    const float* m_b2 = (const float*)d_in[20];
    const float* m_w3 = (const float*)d_in[21];
    const float* m_b3 = (const float*)d_in[22];

    const int N = in_sizes[0];   // 50000 nodes
    const int E = in_sizes[2];   // 1600000 edges
    const int G = out_size;      // 512 graphs

    float* agg = (float*)d_ws;        // N floats
    float* rd  = agg + N;             // G floats
    float* out = (float*)d_out;

    hipMemsetAsync(d_ws, 0, (size_t)(N + G) * sizeof(float), stream);

    int nblk = (E + 255) / 256;
    if (nblk > 2048) nblk = 2048;
    edge_mfma_kernel<<<nblk, 256, 0, stream>>>(
        nf, ef, src, dst, e_w1, e_b1, e_w2, e_b2, e_w3, e_b3, agg, E);

    node_kernel<<<(N + 255) / 256, 256, 0, stream>>>(
        nf, agg, gid,
        n_w1, n_b1, n_w2, n_b2, n_w3, n_b3,
        m_w1, m_b1, m_w2, m_b2, m_w3, m_b3,
        rd, N);

    readout_kernel<<<(G + 255) / 256, 256, 0, stream>>>(rd, out, G);
}

// Round 3
// 153.665 us; speedup vs baseline: 1.4641x; 1.1808x over previous
//
#include <hip/hip_runtime.h>
#include <math.h>

#define HID 64

typedef __attribute__((ext_vector_type(8))) short short8;
typedef __attribute__((ext_vector_type(4))) float f32x4;

union FragU {
    uint4 q;
    short8 v;
    uint32_t u[4];
};

__device__ __forceinline__ uint32_t cvt_pk_bf16(float lo, float hi) {
    uint32_t r;
    asm("v_cvt_pk_bf16_f32 %0, %1, %2" : "=v"(r) : "v"(lo), "v"(hi));
    return r;
}

// ---------------------------------------------------------------------------
// Edge stage (MFMA): msg = MLP3([nf[src], nf[dst], ef]) ; agg[dst] += msg
// (unchanged from round 2 — ~40 us)
// ---------------------------------------------------------------------------
__global__ __launch_bounds__(256) void edge_mfma_kernel(
    const float* __restrict__ nf, const float* __restrict__ ef,
    const int* __restrict__ src, const int* __restrict__ dst,
    const float* __restrict__ w1, const float* __restrict__ b1,
    const float* __restrict__ w2, const float* __restrict__ b2,
    const float* __restrict__ w3, const float* __restrict__ b3,
    float* __restrict__ agg, int E)
{
    __shared__ uint4 hbuf[256 * 8];

    const int tid  = threadIdx.x;
    const int lane = tid & 63;
    const int wid  = tid >> 6;
    const int g    = lane >> 4;
    const int eL   = lane & 15;

    FragU af[4][2];
#pragma unroll
    for (int t = 0; t < 4; ++t)
#pragma unroll
        for (int h = 0; h < 2; ++h)
#pragma unroll
            for (int e2 = 0; e2 < 4; ++e2) {
                int k0 = h * 32 + g * 8 + 2 * e2;
                float v0 = w2[(k0    ) * HID + t * 16 + eL];
                float v1 = w2[(k0 + 1) * HID + t * 16 + eL];
                af[t][h].u[e2] = cvt_pk_bf16(v0, v1);
            }

    float b2v[16], w3v[16];
#pragma unroll
    for (int t = 0; t < 4; ++t)
#pragma unroll
        for (int r = 0; r < 4; ++r) {
            int j = t * 16 + g * 4 + r;
            b2v[t * 4 + r] = b2[j];
            w3v[t * 4 + r] = w3[j];
        }
    const float b3c = b3[0];

    for (int e0 = blockIdx.x * 256; e0 < E; e0 += gridDim.x * 256) {
        int eidx = e0 + tid;
        int ei = eidx < E ? eidx : E - 1;
        float a = nf[src[ei]];
        float b = nf[dst[ei]];
        float c = ef[ei];

        uint32_t pk[32];
#pragma unroll
        for (int k2 = 0; k2 < 32; ++k2) {
            int k0 = 2 * k2, k1 = 2 * k2 + 1;
            float h0 = fmaxf(fmaf(a, w1[k0], fmaf(b, w1[HID + k0], fmaf(c, w1[2 * HID + k0], b1[k0]))), 0.f);
            float h1 = fmaxf(fmaf(a, w1[k1], fmaf(b, w1[HID + k1], fmaf(c, w1[2 * HID + k1], b1[k1]))), 0.f);
            pk[k2] = cvt_pk_bf16(h0, h1);
        }

        __syncthreads();
        {
            uint4* rowp = &hbuf[tid * 8];
            int sw = tid & 7;
#pragma unroll
            for (int ch = 0; ch < 8; ++ch)
                rowp[ch ^ sw] = make_uint4(pk[4 * ch], pk[4 * ch + 1], pk[4 * ch + 2], pk[4 * ch + 3]);
        }
        __syncthreads();

#pragma unroll
        for (int s = 0; s < 4; ++s) {
            int row = wid * 64 + s * 16 + eL;
            int sw  = lane & 7;
            FragU bf0, bf1;
            bf0.q = hbuf[row * 8 + ((    g) ^ sw)];
            bf1.q = hbuf[row * 8 + ((4 + g) ^ sw)];

            f32x4 ac[4];
#pragma unroll
            for (int t = 0; t < 4; ++t) {
                ac[t][0] = b2v[t * 4 + 0];
                ac[t][1] = b2v[t * 4 + 1];
                ac[t][2] = b2v[t * 4 + 2];
                ac[t][3] = b2v[t * 4 + 3];
                ac[t] = __builtin_amdgcn_mfma_f32_16x16x32_bf16(af[t][0].v, bf0.v, ac[t], 0, 0, 0);
                ac[t] = __builtin_amdgcn_mfma_f32_16x16x32_bf16(af[t][1].v, bf1.v, ac[t], 0, 0, 0);
            }

            float p = 0.f;
#pragma unroll
            for (int t = 0; t < 4; ++t)
#pragma unroll
                for (int r = 0; r < 4; ++r)
                    p = fmaf(fmaxf(ac[t][r], 0.f), w3v[t * 4 + r], p);

            p += __shfl_xor(p, 16);
            p += __shfl_xor(p, 32);

            if (lane < 16) {
                int ge = e0 + wid * 64 + s * 16 + lane;
                if (ge < E)
                    atomicAdd(&agg[dst[ge]], p + b3c);
            }
        }
    }
}

// ---------------------------------------------------------------------------
// Node stage (MFMA): unf = MLP3([nf, agg]) ; node_out = sigmoid(MLP3(unf)) ;
// rd[graph_id] += node_out.
// Per wave: 64 nodes. Each MLP uses the edge-kernel pattern: layer1 on VALU
// -> bf16 -> wave-local swizzled LDS tile -> mfma_f32_16x16x32_bf16 with
// A = W2^T, layer3 folded into epilogue + shfl reduce. unf passes between
// the two MLPs via a wave-local LDS array (no barriers needed anywhere:
// every hbuf/unfbuf row is written and read by the same wave).
// Accumulators are f32x4[4] (16 VGPR) -- no 64-wide per-thread array to spill.
// ---------------------------------------------------------------------------
__global__ __launch_bounds__(256) void node_mfma_kernel(
    const float* __restrict__ nf, const float* __restrict__ agg,
    const int* __restrict__ gid,
    const float* __restrict__ nw1, const float* __restrict__ nb1,
    const float* __restrict__ nw2, const float* __restrict__ nb2,
    const float* __restrict__ nw3, const float* __restrict__ nb3,
    const float* __restrict__ mw1, const float* __restrict__ mb1,
    const float* __restrict__ mw2, const float* __restrict__ mb2,
    const float* __restrict__ mw3, const float* __restrict__ mb3,
    float* __restrict__ rd, int N)
{
    __shared__ uint4 hbuf[256 * 8];
    __shared__ float unfbuf[256];

    const int tid  = threadIdx.x;
    const int lane = tid & 63;
    const int wid  = tid >> 6;
    const int g    = lane >> 4;
    const int eL   = lane & 15;
    const int swT  = tid & 7;
    const int swL  = lane & 7;

    const int idx = blockIdx.x * 256 + tid;
    const int i   = idx < N ? idx : N - 1;
    const float x0 = nf[i];
    const float x1 = agg[i];

    // ================= MLP-N: [nf, agg] -> unf =================
    {
        uint32_t pk[32];
#pragma unroll
        for (int k2 = 0; k2 < 32; ++k2) {
            int k0 = 2 * k2, k1 = 2 * k2 + 1;
            float h0 = fmaxf(fmaf(x0, nw1[k0], fmaf(x1, nw1[HID + k0], nb1[k0])), 0.f);
            float h1 = fmaxf(fmaf(x0, nw1[k1], fmaf(x1, nw1[HID + k1], nb1[k1])), 0.f);
            pk[k2] = cvt_pk_bf16(h0, h1);
        }
        uint4* rowp = &hbuf[tid * 8];
#pragma unroll
        for (int ch = 0; ch < 8; ++ch)
            rowp[ch ^ swT] = make_uint4(pk[4 * ch], pk[4 * ch + 1], pk[4 * ch + 2], pk[4 * ch + 3]);

        FragU af[4][2];
#pragma unroll
        for (int t = 0; t < 4; ++t)
#pragma unroll
            for (int h = 0; h < 2; ++h)
#pragma unroll
                for (int e2 = 0; e2 < 4; ++e2) {
                    int k0 = h * 32 + g * 8 + 2 * e2;
                    float v0 = nw2[(k0    ) * HID + t * 16 + eL];
                    float v1 = nw2[(k0 + 1) * HID + t * 16 + eL];
                    af[t][h].u[e2] = cvt_pk_bf16(v0, v1);
                }
        float b2v[16], w3v[16];
#pragma unroll
        for (int t = 0; t < 4; ++t)
#pragma unroll
            for (int r = 0; r < 4; ++r) {
                int j = t * 16 + g * 4 + r;
                b2v[t * 4 + r] = nb2[j];
                w3v[t * 4 + r] = nw3[j];
            }
        const float b3c = nb3[0];

#pragma unroll
        for (int s = 0; s < 4; ++s) {
            int row = wid * 64 + s * 16 + eL;
            FragU bf0, bf1;
            bf0.q = hbuf[row * 8 + ((    g) ^ swL)];
            bf1.q = hbuf[row * 8 + ((4 + g) ^ swL)];

            f32x4 ac[4];
#pragma unroll
            for (int t = 0; t < 4; ++t) {
                ac[t][0] = b2v[t * 4 + 0];
                ac[t][1] = b2v[t * 4 + 1];
                ac[t][2] = b2v[t * 4 + 2];
                ac[t][3] = b2v[t * 4 + 3];
                ac[t] = __builtin_amdgcn_mfma_f32_16x16x32_bf16(af[t][0].v, bf0.v, ac[t], 0, 0, 0);
                ac[t] = __builtin_amdgcn_mfma_f32_16x16x32_bf16(af[t][1].v, bf1.v, ac[t], 0, 0, 0);
            }

            float p = 0.f;
#pragma unroll
            for (int t = 0; t < 4; ++t)
#pragma unroll
                for (int r = 0; r < 4; ++r)
                    p = fmaf(fmaxf(ac[t][r], 0.f), w3v[t * 4 + r], p);

            p += __shfl_xor(p, 16);
            p += __shfl_xor(p, 32);

            if (lane < 16)
                unfbuf[wid * 64 + s * 16 + lane] = p + b3c;
        }
    }

    const float unf = unfbuf[tid];   // wave-local: written by this wave above

    // ================= MLP-M: unf -> sigmoid(out) =================
    {
        uint32_t pk[32];
#pragma unroll
        for (int k2 = 0; k2 < 32; ++k2) {
            int k0 = 2 * k2, k1 = 2 * k2 + 1;
            float h0 = fmaxf(fmaf(unf, mw1[k0], mb1[k0]), 0.f);
            float h1 = fmaxf(fmaf(unf, mw1[k1], mb1[k1]), 0.f);
            pk[k2] = cvt_pk_bf16(h0, h1);
        }
        uint4* rowp = &hbuf[tid * 8];
#pragma unroll
        for (int ch = 0; ch < 8; ++ch)
            rowp[ch ^ swT] = make_uint4(pk[4 * ch], pk[4 * ch + 1], pk[4 * ch + 2], pk[4 * ch + 3]);

        FragU af[4][2];
#pragma unroll
        for (int t = 0; t < 4; ++t)
#pragma unroll
            for (int h = 0; h < 2; ++h)
#pragma unroll
                for (int e2 = 0; e2 < 4; ++e2) {
                    int k0 = h * 32 + g * 8 + 2 * e2;
                    float v0 = mw2[(k0    ) * HID + t * 16 + eL];
                    float v1 = mw2[(k0 + 1) * HID + t * 16 + eL];
                    af[t][h].u[e2] = cvt_pk_bf16(v0, v1);
                }
        float b2v[16], w3v[16];
#pragma unroll
        for (int t = 0; t < 4; ++t)
#pragma unroll
            for (int r = 0; r < 4; ++r) {
                int j = t * 16 + g * 4 + r;
                b2v[t * 4 + r] = mb2[j];
                w3v[t * 4 + r] = mw3[j];
            }
        const float b3c = mb3[0];

#pragma unroll
        for (int s = 0; s < 4; ++s) {
            int row = wid * 64 + s * 16 + eL;
            FragU bf0, bf1;
            bf0.q = hbuf[row * 8 + ((    g) ^ swL)];
            bf1.q = hbuf[row * 8 + ((4 + g) ^ swL)];

            f32x4 ac[4];
#pragma unroll
            for (int t = 0; t < 4; ++t) {
                ac[t][0] = b2v[t * 4 + 0];
                ac[t][1] = b2v[t * 4 + 1];
                ac[t][2] = b2v[t * 4 + 2];
                ac[t][3] = b2v[t * 4 + 3];
                ac[t] = __builtin_amdgcn_mfma_f32_16x16x32_bf16(af[t][0].v, bf0.v, ac[t], 0, 0, 0);
                ac[t] = __builtin_amdgcn_mfma_f32_16x16x32_bf16(af[t][1].v, bf1.v, ac[t], 0, 0, 0);
            }

            float p = 0.f;
#pragma unroll
            for (int t = 0; t < 4; ++t)
#pragma unroll
                for (int r = 0; r < 4; ++r)
                    p = fmaf(fmaxf(ac[t][r], 0.f), w3v[t * 4 + r], p);

            p += __shfl_xor(p, 16);
            p += __shfl_xor(p, 32);

            if (lane < 16) {
                int node = blockIdx.x * 256 + wid * 64 + s * 16 + lane;
                if (node < N) {
                    float o = p + b3c;
                    float node_out = 1.0f / (1.0f + expf(-o));
                    atomicAdd(&rd[gid[node]], node_out);
                }
            }
        }
    }
}

// ---------------------------------------------------------------------------
// Readout: out[g] = sigmoid(rd[g])
// ---------------------------------------------------------------------------
__global__ void readout_kernel(const float* __restrict__ rd,
                               float* __restrict__ out, int G)
{
    int g = blockIdx.x * blockDim.x + threadIdx.x;
    if (g < G) out[g] = 1.0f / (1.0f + expf(-rd[g]));
}

extern "C" void kernel_launch(void* const* d_in, const int* in_sizes, int n_in,
                              void* d_out, int out_size, void* d_ws, size_t ws_size,
                              hipStream_t stream)
{
    const float* nf  = (const float*)d_in[0];
    const float* ef  = (const float*)d_in[1];
    const int*   src = (const int*)  d_in[2];
    const int*   dst = (const int*)  d_in[3];
    const int*   gid = (const int*)  d_in[4];

    const float* e_w1 = (const float*)d_in[5];
    const float* e_b1 = (const float*)d_in[6];
    const float* e_w2 = (const float*)d_in[7];
    const float* e_b2 = (const float*)d_in[8];
    const float* e_w3 = (const float*)d_in[9];
    const float* e_b3 = (const float*)d_in[10];

    const float* n_w1 = (const float*)d_in[11];
    const float* n_b1 = (const float*)d_in[12];
    const float* n_w2 = (const float*)d_in[13];
    const float* n_b2 = (const float*)d_in[14];
    const float* n_w3 = (const float*)d_in[15];
    const float* n_b3 = (const float*)d_in[16];

    const float* m_w1 = (const float*)d_in[17];
    const float* m_b1 = (const float*)d_in[18];
    const float* m_w2 = (const float*)d_in[19];
    const float* m_b2 = (const float*)d_in[20];
    const float* m_w3 = (const float*)d_in[21];
    const float* m_b3 = (const float*)d_in[22];

    const int N = in_sizes[0];   // 50000 nodes
    const int E = in_sizes[2];   // 1600000 edges
    const int G = out_size;      // 512 graphs

    float* agg = (float*)d_ws;        // N floats
    float* rd  = agg + N;             // G floats
    float* out = (float*)d_out;

    hipMemsetAsync(d_ws, 0, (size_t)(N + G) * sizeof(float), stream);

    int nblk = (E + 255) / 256;
    if (nblk > 2048) nblk = 2048;
    edge_mfma_kernel<<<nblk, 256, 0, stream>>>(
        nf, ef, src, dst, e_w1, e_b1, e_w2, e_b2, e_w3, e_b3, agg, E);

    node_mfma_kernel<<<(N + 255) / 256, 256, 0, stream>>>(
        nf, agg, gid,
        n_w1, n_b1, n_w2, n_b2, n_w3, n_b3,
        m_w1, m_b1, m_w2, m_b2, m_w3, m_b3,
        rd, N);

    readout_kernel<<<(G + 255) / 256, 256, 0, stream>>>(rd, out, G);
}

// Round 4
// 113.336 us; speedup vs baseline: 1.9850x; 1.3558x over previous
//
#include <hip/hip_runtime.h>
#include <math.h>

#define HID 64

typedef __attribute__((ext_vector_type(8))) short short8;
typedef __attribute__((ext_vector_type(4))) float f32x4;

union FragU {
    uint4 q;
    short8 v;
    uint32_t u[4];
};

__device__ __forceinline__ uint32_t cvt_pk_bf16(float lo, float hi) {
    uint32_t r;
    asm("v_cvt_pk_bf16_f32 %0, %1, %2" : "=v"(r) : "v"(lo), "v"(hi));
    return r;
}

// ---------------------------------------------------------------------------
// Edge stage (MFMA): msg = MLP3([nf[src], nf[dst], ef]) ; agg[dst] += msg
// One 256-edge batch per block, NO barriers (all LDS traffic is wave-local:
// wave w writes rows w*64..w*64+63 and reads only those), full grid so the
// dependent gather chain is hidden by block-level parallelism instead of a
// serial grid-stride loop.
// ---------------------------------------------------------------------------
__global__ __launch_bounds__(256) void edge_mfma_kernel(
    const float* __restrict__ nf, const float* __restrict__ ef,
    const int* __restrict__ src, const int* __restrict__ dst,
    const float* __restrict__ w1, const float* __restrict__ b1,
    const float* __restrict__ w2, const float* __restrict__ b2,
    const float* __restrict__ w3, const float* __restrict__ b3,
    float* __restrict__ agg, int E)
{
    __shared__ uint4 hbuf[256 * 8];

    const int tid  = threadIdx.x;
    const int lane = tid & 63;
    const int wid  = tid >> 6;
    const int g    = lane >> 4;
    const int eL   = lane & 15;

    // A-fragments = W2^T
    FragU af[4][2];
#pragma unroll
    for (int t = 0; t < 4; ++t)
#pragma unroll
        for (int h = 0; h < 2; ++h)
#pragma unroll
            for (int e2 = 0; e2 < 4; ++e2) {
                int k0 = h * 32 + g * 8 + 2 * e2;
                float v0 = w2[(k0    ) * HID + t * 16 + eL];
                float v1 = w2[(k0 + 1) * HID + t * 16 + eL];
                af[t][h].u[e2] = cvt_pk_bf16(v0, v1);
            }

    float b2v[16], w3v[16];
#pragma unroll
    for (int t = 0; t < 4; ++t)
#pragma unroll
        for (int r = 0; r < 4; ++r) {
            int j = t * 16 + g * 4 + r;
            b2v[t * 4 + r] = b2[j];
            w3v[t * 4 + r] = w3[j];
        }
    const float b3c = b3[0];

    const int e0 = blockIdx.x * 256;
    {
        int eidx = e0 + tid;
        int ei = eidx < E ? eidx : E - 1;
        float a = nf[src[ei]];
        float b = nf[dst[ei]];
        float c = ef[ei];

        // layer 1 on VALU -> packed bf16
        uint32_t pk[32];
#pragma unroll
        for (int k2 = 0; k2 < 32; ++k2) {
            int k0 = 2 * k2, k1 = 2 * k2 + 1;
            float h0 = fmaxf(fmaf(a, w1[k0], fmaf(b, w1[HID + k0], fmaf(c, w1[2 * HID + k0], b1[k0]))), 0.f);
            float h1 = fmaxf(fmaf(a, w1[k1], fmaf(b, w1[HID + k1], fmaf(c, w1[2 * HID + k1], b1[k1]))), 0.f);
            pk[k2] = cvt_pk_bf16(h0, h1);
        }

        // wave-local LDS stage (xor-swizzled 16B chunks), no barrier needed
        uint4* rowp = &hbuf[tid * 8];
        int sw = tid & 7;
#pragma unroll
        for (int ch = 0; ch < 8; ++ch)
            rowp[ch ^ sw] = make_uint4(pk[4 * ch], pk[4 * ch + 1], pk[4 * ch + 2], pk[4 * ch + 3]);
    }

    // layer 2 (MFMA) + layer 3 epilogue
#pragma unroll
    for (int s = 0; s < 4; ++s) {
        int row = wid * 64 + s * 16 + eL;
        int sw  = lane & 7;             // == row & 7
        FragU bf0, bf1;
        bf0.q = hbuf[row * 8 + ((    g) ^ sw)];
        bf1.q = hbuf[row * 8 + ((4 + g) ^ sw)];

        f32x4 ac[4];
#pragma unroll
        for (int t = 0; t < 4; ++t) {
            ac[t][0] = b2v[t * 4 + 0];
            ac[t][1] = b2v[t * 4 + 1];
            ac[t][2] = b2v[t * 4 + 2];
            ac[t][3] = b2v[t * 4 + 3];
            ac[t] = __builtin_amdgcn_mfma_f32_16x16x32_bf16(af[t][0].v, bf0.v, ac[t], 0, 0, 0);
            ac[t] = __builtin_amdgcn_mfma_f32_16x16x32_bf16(af[t][1].v, bf1.v, ac[t], 0, 0, 0);
        }

        float p = 0.f;
#pragma unroll
        for (int t = 0; t < 4; ++t)
#pragma unroll
            for (int r = 0; r < 4; ++r)
                p = fmaf(fmaxf(ac[t][r], 0.f), w3v[t * 4 + r], p);

        p += __shfl_xor(p, 16);
        p += __shfl_xor(p, 32);

        if (lane < 16) {
            int ge = e0 + wid * 64 + s * 16 + lane;
            if (ge < E)
                atomicAdd(&agg[dst[ge]], p + b3c);
        }
    }
}

// ---------------------------------------------------------------------------
// Node stage (MFMA): 1 wave per block, 64 nodes. Same MFMA MLP pattern,
// all LDS wave-local (no barriers). graph_id is SORTED -> segmented
// shfl_up scan across the 64 lanes, one atomicAdd per gid-run tail
// (~25x fewer rd atomics, which are 98-way contended otherwise).
// ---------------------------------------------------------------------------
__global__ __launch_bounds__(64) void node_mfma_kernel(
    const float* __restrict__ nf, const float* __restrict__ agg,
    const int* __restrict__ gid,
    const float* __restrict__ nw1, const float* __restrict__ nb1,
    const float* __restrict__ nw2, const float* __restrict__ nb2,
    const float* __restrict__ nw3, const float* __restrict__ nb3,
    const float* __restrict__ mw1, const float* __restrict__ mb1,
    const float* __restrict__ mw2, const float* __restrict__ mb2,
    const float* __restrict__ mw3, const float* __restrict__ mb3,
    float* __restrict__ rd, int N)
{
    __shared__ uint4 hbuf[64 * 8];
    __shared__ float unfbuf[64];
    __shared__ float obuf[64];

    const int lane = threadIdx.x;
    const int g    = lane >> 4;
    const int eL   = lane & 15;
    const int sw   = lane & 7;

    const int base = blockIdx.x * 64;
    const int idx  = base + lane;
    const int i    = idx < N ? idx : N - 1;
    const float x0 = nf[i];
    const float x1 = agg[i];

    // ================= MLP-N: [nf, agg] -> unf =================
    {
        uint32_t pk[32];
#pragma unroll
        for (int k2 = 0; k2 < 32; ++k2) {
            int k0 = 2 * k2, k1 = 2 * k2 + 1;
            float h0 = fmaxf(fmaf(x0, nw1[k0], fmaf(x1, nw1[HID + k0], nb1[k0])), 0.f);
            float h1 = fmaxf(fmaf(x0, nw1[k1], fmaf(x1, nw1[HID + k1], nb1[k1])), 0.f);
            pk[k2] = cvt_pk_bf16(h0, h1);
        }
        uint4* rowp = &hbuf[lane * 8];
#pragma unroll
        for (int ch = 0; ch < 8; ++ch)
            rowp[ch ^ sw] = make_uint4(pk[4 * ch], pk[4 * ch + 1], pk[4 * ch + 2], pk[4 * ch + 3]);

        FragU af[4][2];
#pragma unroll
        for (int t = 0; t < 4; ++t)
#pragma unroll
            for (int h = 0; h < 2; ++h)
#pragma unroll
                for (int e2 = 0; e2 < 4; ++e2) {
                    int k0 = h * 32 + g * 8 + 2 * e2;
                    float v0 = nw2[(k0    ) * HID + t * 16 + eL];
                    float v1 = nw2[(k0 + 1) * HID + t * 16 + eL];
                    af[t][h].u[e2] = cvt_pk_bf16(v0, v1);
                }
        float b2v[16], w3v[16];
#pragma unroll
        for (int t = 0; t < 4; ++t)
#pragma unroll
            for (int r = 0; r < 4; ++r) {
                int j = t * 16 + g * 4 + r;
                b2v[t * 4 + r] = nb2[j];
                w3v[t * 4 + r] = nw3[j];
            }
        const float b3c = nb3[0];

#pragma unroll
        for (int s = 0; s < 4; ++s) {
            int row = s * 16 + eL;
            FragU bf0, bf1;
            bf0.q = hbuf[row * 8 + ((    g) ^ (row & 7))];
            bf1.q = hbuf[row * 8 + ((4 + g) ^ (row & 7))];

            f32x4 ac[4];
#pragma unroll
            for (int t = 0; t < 4; ++t) {
                ac[t][0] = b2v[t * 4 + 0];
                ac[t][1] = b2v[t * 4 + 1];
                ac[t][2] = b2v[t * 4 + 2];
                ac[t][3] = b2v[t * 4 + 3];
                ac[t] = __builtin_amdgcn_mfma_f32_16x16x32_bf16(af[t][0].v, bf0.v, ac[t], 0, 0, 0);
                ac[t] = __builtin_amdgcn_mfma_f32_16x16x32_bf16(af[t][1].v, bf1.v, ac[t], 0, 0, 0);
            }

            float p = 0.f;
#pragma unroll
            for (int t = 0; t < 4; ++t)
#pragma unroll
                for (int r = 0; r < 4; ++r)
                    p = fmaf(fmaxf(ac[t][r], 0.f), w3v[t * 4 + r], p);

            p += __shfl_xor(p, 16);
            p += __shfl_xor(p, 32);

            if (lane < 16)
                unfbuf[s * 16 + lane] = p + b3c;
        }
    }

    const float unf = unfbuf[lane];   // wave-local

    // ================= MLP-M: unf -> sigmoid(out) =================
    {
        uint32_t pk[32];
#pragma unroll
        for (int k2 = 0; k2 < 32; ++k2) {
            int k0 = 2 * k2, k1 = 2 * k2 + 1;
            float h0 = fmaxf(fmaf(unf, mw1[k0], mb1[k0]), 0.f);
            float h1 = fmaxf(fmaf(unf, mw1[k1], mb1[k1]), 0.f);
            pk[k2] = cvt_pk_bf16(h0, h1);
        }
        uint4* rowp = &hbuf[lane * 8];
#pragma unroll
        for (int ch = 0; ch < 8; ++ch)
            rowp[ch ^ sw] = make_uint4(pk[4 * ch], pk[4 * ch + 1], pk[4 * ch + 2], pk[4 * ch + 3]);

        FragU af[4][2];
#pragma unroll
        for (int t = 0; t < 4; ++t)
#pragma unroll
            for (int h = 0; h < 2; ++h)
#pragma unroll
                for (int e2 = 0; e2 < 4; ++e2) {
                    int k0 = h * 32 + g * 8 + 2 * e2;
                    float v0 = mw2[(k0    ) * HID + t * 16 + eL];
                    float v1 = mw2[(k0 + 1) * HID + t * 16 + eL];
                    af[t][h].u[e2] = cvt_pk_bf16(v0, v1);
                }
        float b2v[16], w3v[16];
#pragma unroll
        for (int t = 0; t < 4; ++t)
#pragma unroll
            for (int r = 0; r < 4; ++r) {
                int j = t * 16 + g * 4 + r;
                b2v[t * 4 + r] = mb2[j];
                w3v[t * 4 + r] = mw3[j];
            }
        const float b3c = mb3[0];

#pragma unroll
        for (int s = 0; s < 4; ++s) {
            int row = s * 16 + eL;
            FragU bf0, bf1;
            bf0.q = hbuf[row * 8 + ((    g) ^ (row & 7))];
            bf1.q = hbuf[row * 8 + ((4 + g) ^ (row & 7))];

            f32x4 ac[4];
#pragma unroll
            for (int t = 0; t < 4; ++t) {
                ac[t][0] = b2v[t * 4 + 0];
                ac[t][1] = b2v[t * 4 + 1];
                ac[t][2] = b2v[t * 4 + 2];
                ac[t][3] = b2v[t * 4 + 3];
                ac[t] = __builtin_amdgcn_mfma_f32_16x16x32_bf16(af[t][0].v, bf0.v, ac[t], 0, 0, 0);
                ac[t] = __builtin_amdgcn_mfma_f32_16x16x32_bf16(af[t][1].v, bf1.v, ac[t], 0, 0, 0);
            }

            float p = 0.f;
#pragma unroll
            for (int t = 0; t < 4; ++t)
#pragma unroll
                for (int r = 0; r < 4; ++r)
                    p = fmaf(fmaxf(ac[t][r], 0.f), w3v[t * 4 + r], p);

            p += __shfl_xor(p, 16);
            p += __shfl_xor(p, 32);

            if (lane < 16) {
                float o = p + b3c;
                obuf[s * 16 + lane] = 1.0f / (1.0f + expf(-o));
            }
        }
    }

    // ---- segmented reduction over sorted gid, one atomic per run tail ----
    {
        const bool ok = idx < N;
        float v = ok ? obuf[lane] : 0.0f;
        int   gg = gid[i];            // clamped index; OOB lanes merge into last run

#pragma unroll
        for (int d = 1; d < 64; d <<= 1) {
            float vup = __shfl_up(v, d);
            int   gup = __shfl_up(gg, d);
            if (lane >= d && gup == gg) v += vup;
        }
        int gdn = __shfl_down(gg, 1);
        bool tail = (lane == 63) || (gdn != gg);
        if (tail)
            atomicAdd(&rd[gg], v);
    }
}

// ---------------------------------------------------------------------------
// Readout: out[g] = sigmoid(rd[g])
// ---------------------------------------------------------------------------
__global__ void readout_kernel(const float* __restrict__ rd,
                               float* __restrict__ out, int G)
{
    int g = blockIdx.x * blockDim.x + threadIdx.x;
    if (g < G) out[g] = 1.0f / (1.0f + expf(-rd[g]));
}

extern "C" void kernel_launch(void* const* d_in, const int* in_sizes, int n_in,
                              void* d_out, int out_size, void* d_ws, size_t ws_size,
                              hipStream_t stream)
{
    const float* nf  = (const float*)d_in[0];
    const float* ef  = (const float*)d_in[1];
    const int*   src = (const int*)  d_in[2];
    const int*   dst = (const int*)  d_in[3];
    const int*   gid = (const int*)  d_in[4];

    const float* e_w1 = (const float*)d_in[5];
    const float* e_b1 = (const float*)d_in[6];
    const float* e_w2 = (const float*)d_in[7];
    const float* e_b2 = (const float*)d_in[8];
    const float* e_w3 = (const float*)d_in[9];
    const float* e_b3 = (const float*)d_in[10];

    const float* n_w1 = (const float*)d_in[11];
    const float* n_b1 = (const float*)d_in[12];
    const float* n_w2 = (const float*)d_in[13];
    const float* n_b2 = (const float*)d_in[14];
    const float* n_w3 = (const float*)d_in[15];
    const float* n_b3 = (const float*)d_in[16];

    const float* m_w1 = (const float*)d_in[17];
    const float* m_b1 = (const float*)d_in[18];
    const float* m_w2 = (const float*)d_in[19];
    const float* m_b2 = (const float*)d_in[20];
    const float* m_w3 = (const float*)d_in[21];
    const float* m_b3 = (const float*)d_in[22];

    const int N = in_sizes[0];   // 50000 nodes
    const int E = in_sizes[2];   // 1600000 edges
    const int G = out_size;      // 512 graphs

    float* agg = (float*)d_ws;        // N floats
    float* rd  = agg + N;             // G floats
    float* out = (float*)d_out;

    hipMemsetAsync(d_ws, 0, (size_t)(N + G) * sizeof(float), stream);

    edge_mfma_kernel<<<(E + 255) / 256, 256, 0, stream>>>(
        nf, ef, src, dst, e_w1, e_b1, e_w2, e_b2, e_w3, e_b3, agg, E);

    node_mfma_kernel<<<(N + 63) / 64, 64, 0, stream>>>(
        nf, agg, gid,
        n_w1, n_b1, n_w2, n_b2, n_w3, n_b3,
        m_w1, m_b1, m_w2, m_b2, m_w3, m_b3,
        rd, N);

    readout_kernel<<<(G + 255) / 256, 256, 0, stream>>>(rd, out, G);
}